// Round 9
// baseline (364.943 us; speedup 1.0000x reference)
//
#include <hip/hip_runtime.h>
#include <math.h>

#define BDIM 2
#define SLEN 2048
#define NH 16
#define NKV 4
#define HD 128

typedef __attribute__((ext_vector_type(8))) short short8v;
typedef __attribute__((ext_vector_type(4))) short short4v;
typedef __attribute__((ext_vector_type(8))) __bf16 bf16x8;
typedef __attribute__((ext_vector_type(4))) float f32x4;

__device__ inline unsigned short f2bf(float x) {
  unsigned int u = __builtin_bit_cast(unsigned int, x);
  unsigned int r = (u + 0x7fffu + ((u >> 16) & 1u)) >> 16;
  return (unsigned short)r;
}
__device__ inline float bf2f(unsigned short b) {
  unsigned int u = ((unsigned int)b) << 16;
  return __builtin_bit_cast(float, u);
}

// ---------------------------------------------------------------------------
// bf16 MFMA GEMM, m97 structure, 128x128 tile (proven).
// ---------------------------------------------------------------------------
template <bool BF16_OUT, bool SPLIT>
__global__ __launch_bounds__(256) void gemm_mfma_bt(
    const unsigned short* __restrict__ A, const unsigned short* __restrict__ Bt,
    void* __restrict__ C0, void* __restrict__ C1,
    int M, int N, int K, int Nsplit, int S0, int S1) {
  __shared__ __align__(16) unsigned short As[128 * 64];
  __shared__ __align__(16) unsigned short Bs[128 * 64];
  const int t    = threadIdx.x;
  const int lane = t & 63;
  const int w    = t >> 6;
  const int lg   = lane >> 4, l15 = lane & 15;
  const int wr   = w >> 1,    wc  = w & 1;
  const int bm = blockIdx.y * 128, bn = blockIdx.x * 128;

  const int srow = w * 32 + (lane >> 3);
  const int scol = (lane & 7) * 8;
  const unsigned short* gA = &A[(size_t)(bm + srow) * K + scol];
  const unsigned short* gB = &Bt[(size_t)(bn + srow) * K + scol];

  f32x4 acc[4][4];
#pragma unroll
  for (int m = 0; m < 4; ++m)
#pragma unroll
    for (int n = 0; n < 4; ++n) acc[m][n] = (f32x4){0.f, 0.f, 0.f, 0.f};

  for (int k0 = 0; k0 < K; k0 += 64) {
    __syncthreads();
#pragma unroll
    for (int i = 0; i < 4; ++i) {
      __builtin_amdgcn_global_load_lds(
          (const __attribute__((address_space(1))) unsigned int*)(gA + (size_t)i * 8 * K + k0),
          (__attribute__((address_space(3))) unsigned int*)&As[(w * 32 + i * 8) * 64],
          16, 0, 0);
      __builtin_amdgcn_global_load_lds(
          (const __attribute__((address_space(1))) unsigned int*)(gB + (size_t)i * 8 * K + k0),
          (__attribute__((address_space(3))) unsigned int*)&Bs[(w * 32 + i * 8) * 64],
          16, 0, 0);
    }
    __syncthreads();
#pragma unroll
    for (int kk = 0; kk < 2; ++kk) {
      bf16x8 a[4], b[4];
#pragma unroll
      for (int m = 0; m < 4; ++m)
        a[m] = __builtin_bit_cast(bf16x8, *reinterpret_cast<const short8v*>(
            &As[(wr * 64 + m * 16 + l15) * 64 + kk * 32 + lg * 8]));
#pragma unroll
      for (int n = 0; n < 4; ++n)
        b[n] = __builtin_bit_cast(bf16x8, *reinterpret_cast<const short8v*>(
            &Bs[(wc * 64 + n * 16 + l15) * 64 + kk * 32 + lg * 8]));
#pragma unroll
      for (int m = 0; m < 4; ++m)
#pragma unroll
        for (int n = 0; n < 4; ++n)
          acc[m][n] = __builtin_amdgcn_mfma_f32_16x16x32_bf16(a[m], b[n], acc[m][n], 0, 0, 0);
    }
  }

  void* dst;
  int col0, stride;
  if (!SPLIT || bn < Nsplit) {
    dst = C0; col0 = bn; stride = S0;
  } else {
    dst = C1; col0 = bn - Nsplit; stride = S1;
  }
#pragma unroll
  for (int m = 0; m < 4; ++m) {
#pragma unroll
    for (int j = 0; j < 4; ++j) {
      const size_t row = (size_t)(bm + wr * 64 + m * 16 + lg * 4 + j);
#pragma unroll
      for (int n = 0; n < 4; ++n) {
        const int col = col0 + wc * 64 + n * 16 + l15;
        if (BF16_OUT)
          ((unsigned short*)dst)[row * stride + col] = f2bf(acc[m][n][j]);
        else
          ((float*)dst)[row * stride + col] = acc[m][n][j];
      }
    }
  }
}

// ---------------------------------------------------------------------------
__global__ __launch_bounds__(256) void transpose_cast(
    const float* __restrict__ W, unsigned short* __restrict__ Wt, int K, int N) {
  __shared__ float tile[32][33];
  const int tx = threadIdx.x & 31, ty = threadIdx.x >> 5;
  const int n0 = blockIdx.x * 32, k0 = blockIdx.y * 32;
#pragma unroll
  for (int i = 0; i < 4; ++i)
    tile[ty + i * 8][tx] = W[(size_t)(k0 + ty + i * 8) * N + n0 + tx];
  __syncthreads();
#pragma unroll
  for (int i = 0; i < 4; ++i)
    Wt[(size_t)(n0 + ty + i * 8) * K + k0 + tx] = f2bf(tile[tx][ty + i * 8]);
}

__global__ __launch_bounds__(256) void cast_f32_bf16(
    const float* __restrict__ in, unsigned short* __restrict__ out) {
  const int i = (blockIdx.x * 256 + threadIdx.x) * 8;
  float4 a = *reinterpret_cast<const float4*>(&in[i]);
  float4 b = *reinterpret_cast<const float4*>(&in[i + 4]);
  short8v s;
  s[0] = f2bf(a.x); s[1] = f2bf(a.y); s[2] = f2bf(a.z); s[3] = f2bf(a.w);
  s[4] = f2bf(b.x); s[5] = f2bf(b.y); s[6] = f2bf(b.z); s[7] = f2bf(b.w);
  *reinterpret_cast<short8v*>(&out[i]) = s;
}

// ---------------------------------------------------------------------------
__global__ __launch_bounds__(256) void rope_xpos_ip(
    unsigned short* __restrict__ buf, int row_stride, int nh_shift, int invert,
    float extra_scale) {
  const int idx = blockIdx.x * 256 + threadIdx.x;
  const int dp  = idx & 63;
  const int tmp = idx >> 6;
  const int h   = tmp & ((1 << nh_shift) - 1);
  const int row = tmp >> nh_shift;
  const int s   = row & (SLEN - 1);

  const float inv_freq = expf(-(float)dp * (9.210340371976184f / 64.0f));
  const float ang = (float)s * inv_freq;
  float sn, cs;
  sincosf(ang, &sn, &cs);

  unsigned short* p = buf + (size_t)row * row_stride + h * HD;
  const float x0 = bf2f(p[dp]);
  const float x1 = bf2f(p[dp + 64]);
  float y0 = x0 * cs - x1 * sn;
  float y1 = x1 * cs + x0 * sn;

  const float scl = ((float)s + 256.0f) / 512.0f;
  float se_even = invert ? (1.0f / scl) : scl;
  float se_odd  = invert ? scl : (1.0f / scl);
  float se = ((dp & 1) ? se_odd : se_even) * extra_scale;

  p[dp]      = f2bf(y0 * se);
  p[dp + 64] = f2bf(y1 * se);
}

// ---------------------------------------------------------------------------
// Flash attention v6: 256 threads (4 waves), QBLK=128, 32 q-rows/wave
// (two 16-row sets). Each K/V fragment read feeds TWO MFMAs -> LDS-issue
// traffic per unit work halved vs v5. Same dbuf/swizzle/defer-max/pairing.
// LDS = 64KB KV dbuf + 16KB Ps = 81920 B (2 blocks/CU).
// ---------------------------------------------------------------------------
__global__ __launch_bounds__(256) void flash_attn_v6(
    const unsigned short* __restrict__ qb, const unsigned short* __restrict__ kvb,
    unsigned short* __restrict__ o) {
  const int bid = blockIdx.x;
  const int u   = bid & 15;
  const int qt2 = (u & 1) ? (15 - (u >> 1)) : (u >> 1);  // balanced pairing
  const int bh  = bid >> 4;
  const int h   = bh & (NH - 1);
  const int b   = bh >> 4;
  const int kvh = h >> 2;

  __shared__ __align__(16) unsigned char smem[81920];
  unsigned short* KsBase = (unsigned short*)smem;            // 2 x 64x128 swz
  unsigned int*   VwBase = (unsigned int*)(smem + 32768);    // 2 x 128x32 swz
  unsigned short* Ps     = (unsigned short*)(smem + 65536);  // 4 x [32][64] swz

  const int t    = threadIdx.x;
  const int lane = t & 63;
  const int w    = t >> 6;   // 0..3
  const int lg   = lane >> 4;
  const int l15  = lane & 15;

  // ---- Q fragments: wave w owns q-rows qt2*128 + w*32 + {s*16 + l15}
  bf16x8 qf0[4], qf1[4];
  {
    const size_t qr0 =
        ((size_t)(b * SLEN + qt2 * 128 + w * 32 + l15)) * (NH * HD) + h * HD;
    const size_t qr1 = qr0 + (size_t)16 * (NH * HD);
#pragma unroll
    for (int kc = 0; kc < 4; ++kc) {
      qf0[kc] = __builtin_bit_cast(bf16x8,
          *reinterpret_cast<const short8v*>(&qb[qr0 + kc * 32 + lg * 8]));
      qf1[kc] = __builtin_bit_cast(bf16x8,
          *reinterpret_cast<const short8v*>(&qb[qr1 + kc * 32 + lg * 8]));
    }
  }

  short8v kreg[4], vreg0[2], vreg1[2];
  const int kr_base = t >> 4, kc8 = t & 15;  // K: rows kr_base+16i, cols kc8*8
  const int vr2 = t & 31, vc8b = t >> 5;     // V: row-pair vr2, col base vc8b

#define LOAD_TILE(kt)                                                          \
  {                                                                            \
    const size_t kbase = ((size_t)(b * SLEN + (kt) * 64)) * 1024 + kvh * 128;  \
    _Pragma("unroll") for (int i = 0; i < 4; ++i)                              \
        kreg[i] = *reinterpret_cast<const short8v*>(                           \
            &kvb[kbase + (size_t)(kr_base + i * 16) * 1024 + kc8 * 8]);        \
    const size_t vbase = kbase + 512;                                          \
    _Pragma("unroll") for (int i = 0; i < 2; ++i) {                            \
      const int c8 = vc8b + i * 8;                                             \
      vreg0[i] = *reinterpret_cast<const short8v*>(                            \
          &kvb[vbase + (size_t)(2 * vr2) * 1024 + c8 * 8]);                    \
      vreg1[i] = *reinterpret_cast<const short8v*>(                            \
          &kvb[vbase + (size_t)(2 * vr2 + 1) * 1024 + c8 * 8]);                \
    }                                                                          \
  }

#define STORE_TILE(bb)                                                         \
  {                                                                            \
    unsigned short* Kb = KsBase + (bb) * 8192;                                 \
    unsigned int*   Vw = VwBase + (bb) * 4096;                                 \
    _Pragma("unroll") for (int i = 0; i < 4; ++i) {                            \
      const int r = kr_base + i * 16;                                          \
      *reinterpret_cast<short8v*>(&Kb[r * 128 + ((kc8 * 8) ^ ((r & 7) << 3))]) \
          = kreg[i];                                                           \
    }                                                                          \
    _Pragma("unroll") for (int i = 0; i < 2; ++i) {                            \
      _Pragma("unroll") for (int j = 0; j < 8; ++j) {                          \
        const int d = (vc8b + i * 8) * 8 + j;                                  \
        unsigned int wv = (unsigned int)(unsigned short)vreg0[i][j] |          \
                          ((unsigned int)(unsigned short)vreg1[i][j] << 16);   \
        Vw[d * 32 + (vr2 ^ ((d & 7) << 2))] = wv;                              \
      }                                                                        \
    }                                                                          \
  }

  f32x4 Oacc0[8], Oacc1[8];
#pragma unroll
  for (int dt = 0; dt < 8; ++dt) {
    Oacc0[dt] = (f32x4){0.f, 0.f, 0.f, 0.f};
    Oacc1[dt] = (f32x4){0.f, 0.f, 0.f, 0.f};
  }
  float m_run0 = -1e30f, l_run0 = 0.f;
  float m_run1 = -1e30f, l_run1 = 0.f;

  const int nt = 2 * qt2 + 2;  // kv tiles for this 128-row q block

  LOAD_TILE(0)
  STORE_TILE(0)
  __syncthreads();
  int cur = 0;

  for (int kt = 0; kt < nt; ++kt) {
    if (kt + 1 < nt) LOAD_TILE(kt + 1)

    const unsigned short* Kb = KsBase + cur * 8192;
    const unsigned int*   Vw = VwBase + cur * 4096;

    // ---- S^T = K @ Q^T for both q-row sets; kf read once, used twice
    f32x4 S0[4], S1[4];
    __builtin_amdgcn_s_setprio(1);
#pragma unroll
    for (int ct = 0; ct < 4; ++ct) {
      f32x4 a0 = (f32x4){0.f, 0.f, 0.f, 0.f};
      f32x4 a1 = (f32x4){0.f, 0.f, 0.f, 0.f};
      const int row = ct * 16 + l15;
#pragma unroll
      for (int kc = 0; kc < 4; ++kc) {
        bf16x8 kf = __builtin_bit_cast(bf16x8, *reinterpret_cast<const short8v*>(
            &Kb[row * 128 + ((kc * 32 + lg * 8) ^ ((row & 7) << 3))]));
        a0 = __builtin_amdgcn_mfma_f32_16x16x32_bf16(kf, qf0[kc], a0, 0, 0, 0);
        a1 = __builtin_amdgcn_mfma_f32_16x16x32_bf16(kf, qf1[kc], a1, 0, 0, 0);
      }
      S0[ct] = a0;
      S1[ct] = a1;
    }
    __builtin_amdgcn_s_setprio(0);

    if (kt >= 2 * qt2) {  // diagonal region
      const int shift = (kt - 2 * qt2) * 64;
      const int ql0 = w * 32 + l15 - shift;
      const int ql1 = ql0 + 16;
#pragma unroll
      for (int ct = 0; ct < 4; ++ct) {
#pragma unroll
        for (int j = 0; j < 4; ++j) {
          const int kl = ct * 16 + lg * 4 + j;
          if (kl > ql0) S0[ct][j] = -1e30f;
          if (kl > ql1) S1[ct][j] = -1e30f;
        }
      }
    }

    // ---- lane-local softmax, set 0
    {
      float pmax = S0[0][0];
#pragma unroll
      for (int ct = 0; ct < 4; ++ct)
#pragma unroll
        for (int j = 0; j < 4; ++j) pmax = fmaxf(pmax, S0[ct][j]);
      pmax = fmaxf(pmax, __shfl_xor(pmax, 16));
      pmax = fmaxf(pmax, __shfl_xor(pmax, 32));
      const bool defer = __all(pmax - m_run0 <= 8.0f);
      float m_new, f;
      if (defer) { m_new = m_run0; f = 1.0f; }
      else { m_new = fmaxf(m_run0, pmax); f = __expf(m_run0 - m_new); m_run0 = m_new; }
      float psum = 0.f;
#pragma unroll
      for (int ct = 0; ct < 4; ++ct) {
        short4v pk;
#pragma unroll
        for (int j = 0; j < 4; ++j) {
          const float pv = __expf(S0[ct][j] - m_new);
          psum += pv;
          pk[j] = (short)f2bf(pv);
        }
        *reinterpret_cast<short4v*>(
            &Ps[w * 2048 + l15 * 64 + ((ct * 16 + lg * 4) ^ ((l15 & 7) << 3))]) = pk;
      }
      psum += __shfl_xor(psum, 16);
      psum += __shfl_xor(psum, 32);
      l_run0 = l_run0 * f + psum;
      if (!defer) {
#pragma unroll
        for (int dt = 0; dt < 8; ++dt)
#pragma unroll
          for (int j = 0; j < 4; ++j) Oacc0[dt][j] *= f;
      }
    }
    // ---- set 1
    {
      float pmax = S1[0][0];
#pragma unroll
      for (int ct = 0; ct < 4; ++ct)
#pragma unroll
        for (int j = 0; j < 4; ++j) pmax = fmaxf(pmax, S1[ct][j]);
      pmax = fmaxf(pmax, __shfl_xor(pmax, 16));
      pmax = fmaxf(pmax, __shfl_xor(pmax, 32));
      const bool defer = __all(pmax - m_run1 <= 8.0f);
      float m_new, f;
      if (defer) { m_new = m_run1; f = 1.0f; }
      else { m_new = fmaxf(m_run1, pmax); f = __expf(m_run1 - m_new); m_run1 = m_new; }
      float psum = 0.f;
#pragma unroll
      for (int ct = 0; ct < 4; ++ct) {
        short4v pk;
#pragma unroll
        for (int j = 0; j < 4; ++j) {
          const float pv = __expf(S1[ct][j] - m_new);
          psum += pv;
          pk[j] = (short)f2bf(pv);
        }
        *reinterpret_cast<short4v*>(
            &Ps[w * 2048 + (16 + l15) * 64 + ((ct * 16 + lg * 4) ^ ((l15 & 7) << 3))]) = pk;
      }
      psum += __shfl_xor(psum, 16);
      psum += __shfl_xor(psum, 32);
      l_run1 = l_run1 * f + psum;
      if (!defer) {
#pragma unroll
        for (int dt = 0; dt < 8; ++dt)
#pragma unroll
          for (int j = 0; j < 4; ++j) Oacc1[dt][j] *= f;
      }
    }

    // ---- O^T += V^T @ P^T ; vf read once, used for both sets
#pragma unroll
    for (int kc = 0; kc < 2; ++kc) {
      bf16x8 pf0 = __builtin_bit_cast(bf16x8, *reinterpret_cast<const short8v*>(
          &Ps[w * 2048 + l15 * 64 + ((kc * 32 + lg * 8) ^ ((l15 & 7) << 3))]));
      bf16x8 pf1 = __builtin_bit_cast(bf16x8, *reinterpret_cast<const short8v*>(
          &Ps[w * 2048 + (16 + l15) * 64 + ((kc * 32 + lg * 8) ^ ((l15 & 7) << 3))]));
      __builtin_amdgcn_s_setprio(1);
#pragma unroll
      for (int dt = 0; dt < 8; ++dt) {
        const int d = dt * 16 + l15;
        bf16x8 vf = __builtin_bit_cast(bf16x8, *reinterpret_cast<const bf16x8*>(
            &Vw[d * 32 + ((kc * 16 + lg * 4) ^ ((d & 7) << 2))]));
        Oacc0[dt] = __builtin_amdgcn_mfma_f32_16x16x32_bf16(vf, pf0, Oacc0[dt], 0, 0, 0);
        Oacc1[dt] = __builtin_amdgcn_mfma_f32_16x16x32_bf16(vf, pf1, Oacc1[dt], 0, 0, 0);
      }
      __builtin_amdgcn_s_setprio(0);
    }

    if (kt + 1 < nt) STORE_TILE(cur ^ 1)
    __syncthreads();
    cur ^= 1;
  }

  // ---- epilogue
  {
    const float linv = 1.0f / l_run0;
    const size_t row = (size_t)(b * SLEN + qt2 * 128 + w * 32 + l15);
#pragma unroll
    for (int dt = 0; dt < 8; ++dt) {
      short4v ov;
#pragma unroll
      for (int j = 0; j < 4; ++j) ov[j] = (short)f2bf(Oacc0[dt][j] * linv);
      *reinterpret_cast<short4v*>(&o[row * 2048 + h * HD + dt * 16 + lg * 4]) = ov;
    }
  }
  {
    const float linv = 1.0f / l_run1;
    const size_t row = (size_t)(b * SLEN + qt2 * 128 + w * 32 + 16 + l15);
#pragma unroll
    for (int dt = 0; dt < 8; ++dt) {
      short4v ov;
#pragma unroll
      for (int j = 0; j < 4; ++j) ov[j] = (short)f2bf(Oacc1[dt][j] * linv);
      *reinterpret_cast<short4v*>(&o[row * 2048 + h * HD + dt * 16 + lg * 4]) = ov;
    }
  }
#undef LOAD_TILE
#undef STORE_TILE
}

// ---------------------------------------------------------------------------
extern "C" void kernel_launch(void* const* d_in, const int* in_sizes, int n_in,
                              void* d_out, int out_size, void* d_ws, size_t ws_size,
                              hipStream_t stream) {
  (void)in_sizes; (void)n_in; (void)out_size; (void)ws_size;
  const float* x  = (const float*)d_in[0];
  const float* Wq = (const float*)d_in[1];
  const float* Wk = (const float*)d_in[2];
  const float* Wv = (const float*)d_in[3];
  const float* Wo = (const float*)d_in[4];
  float* out = (float*)d_out;

  unsigned char* ws = (unsigned char*)d_ws;
  const size_t MB = 1024 * 1024;
  unsigned short* xb    = (unsigned short*)(ws);            // 16 MB 4096x2048
  unsigned short* Wqkvt = (unsigned short*)(ws + 16 * MB);  // 12 MB 3072x2048
  unsigned short* Wot   = (unsigned short*)(ws + 28 * MB);  //  8 MB 2048x2048
  unsigned short* qb    = (unsigned short*)(ws + 36 * MB);  // 16 MB 4096x2048
  unsigned short* kvb   = (unsigned short*)(ws + 52 * MB);  //  8 MB 4096x1024
  unsigned short* attn  = (unsigned short*)(ws + 60 * MB);  // 16 MB

  const int M = BDIM * SLEN;  // 4096
  dim3 blk(256);

  cast_f32_bf16<<<(M * 2048) / (256 * 8), blk, 0, stream>>>(x, xb);
  transpose_cast<<<dim3(64, 64), blk, 0, stream>>>(Wq, Wqkvt, 2048, 2048);
  transpose_cast<<<dim3(16, 64), blk, 0, stream>>>(
      Wk, Wqkvt + (size_t)2048 * 2048, 2048, 512);
  transpose_cast<<<dim3(16, 64), blk, 0, stream>>>(
      Wv, Wqkvt + (size_t)2560 * 2048, 2048, 512);
  transpose_cast<<<dim3(64, 64), blk, 0, stream>>>(Wo, Wot, 2048, 2048);

  gemm_mfma_bt<true, true><<<dim3(24, 32), blk, 0, stream>>>(
      xb, Wqkvt, qb, kvb, M, 3072, 2048, 2048, 2048, 1024);

  rope_xpos_ip<<<(M * NH * 64) / 256, blk, 0, stream>>>(
      qb, 2048, 4, 0, 0.088388347648318447f);
  rope_xpos_ip<<<(M * NKV * 64) / 256, blk, 0, stream>>>(kvb, 1024, 2, 1, 1.0f);

  flash_attn_v6<<<BDIM * NH * (SLEN / 128), blk, 0, stream>>>(qb, kvb, attn);

  gemm_mfma_bt<false, false><<<dim3(16, 32), blk, 0, stream>>>(
      attn, Wot, out, nullptr, M, 2048, 2048, 2048, 2048, 0);
}

// Round 10
// 279.867 us; speedup vs baseline: 1.3040x; 1.3040x over previous
//
#include <hip/hip_runtime.h>
#include <math.h>

#define BDIM 2
#define SLEN 2048
#define NH 16
#define NKV 4
#define HD 128

typedef __attribute__((ext_vector_type(8))) short short8v;
typedef __attribute__((ext_vector_type(4))) short short4v;
typedef __attribute__((ext_vector_type(8))) __bf16 bf16x8;
typedef __attribute__((ext_vector_type(4))) float f32x4;
typedef __attribute__((ext_vector_type(16))) float f32x16;
typedef __attribute__((ext_vector_type(4))) unsigned int u32x4;

__device__ inline unsigned short f2bf(float x) {
  unsigned int u = __builtin_bit_cast(unsigned int, x);
  unsigned int r = (u + 0x7fffu + ((u >> 16) & 1u)) >> 16;
  return (unsigned short)r;
}
__device__ inline float bf2f(unsigned short b) {
  unsigned int u = ((unsigned int)b) << 16;
  return __builtin_bit_cast(float, u);
}
__device__ inline unsigned int pk2(float a, float b) {
  unsigned short ua = __builtin_bit_cast(unsigned short, (__bf16)a);
  unsigned short ub = __builtin_bit_cast(unsigned short, (__bf16)b);
  return (unsigned int)ua | ((unsigned int)ub << 16);
}

// ---------------------------------------------------------------------------
// bf16 MFMA GEMM, m97 structure, 128x128 tile (proven, unchanged from R8).
// ---------------------------------------------------------------------------
template <bool BF16_OUT, bool SPLIT>
__global__ __launch_bounds__(256) void gemm_mfma_bt(
    const unsigned short* __restrict__ A, const unsigned short* __restrict__ Bt,
    void* __restrict__ C0, void* __restrict__ C1,
    int M, int N, int K, int Nsplit, int S0, int S1) {
  __shared__ __align__(16) unsigned short As[128 * 64];
  __shared__ __align__(16) unsigned short Bs[128 * 64];
  const int t    = threadIdx.x;
  const int lane = t & 63;
  const int w    = t >> 6;
  const int lg   = lane >> 4, l15 = lane & 15;
  const int wr   = w >> 1,    wc  = w & 1;
  const int bm = blockIdx.y * 128, bn = blockIdx.x * 128;

  const int srow = w * 32 + (lane >> 3);
  const int scol = (lane & 7) * 8;
  const unsigned short* gA = &A[(size_t)(bm + srow) * K + scol];
  const unsigned short* gB = &Bt[(size_t)(bn + srow) * K + scol];

  f32x4 acc[4][4];
#pragma unroll
  for (int m = 0; m < 4; ++m)
#pragma unroll
    for (int n = 0; n < 4; ++n) acc[m][n] = (f32x4){0.f, 0.f, 0.f, 0.f};

  for (int k0 = 0; k0 < K; k0 += 64) {
    __syncthreads();
#pragma unroll
    for (int i = 0; i < 4; ++i) {
      __builtin_amdgcn_global_load_lds(
          (const __attribute__((address_space(1))) unsigned int*)(gA + (size_t)i * 8 * K + k0),
          (__attribute__((address_space(3))) unsigned int*)&As[(w * 32 + i * 8) * 64],
          16, 0, 0);
      __builtin_amdgcn_global_load_lds(
          (const __attribute__((address_space(1))) unsigned int*)(gB + (size_t)i * 8 * K + k0),
          (__attribute__((address_space(3))) unsigned int*)&Bs[(w * 32 + i * 8) * 64],
          16, 0, 0);
    }
    __syncthreads();
#pragma unroll
    for (int kk = 0; kk < 2; ++kk) {
      bf16x8 a[4], b[4];
#pragma unroll
      for (int m = 0; m < 4; ++m)
        a[m] = __builtin_bit_cast(bf16x8, *reinterpret_cast<const short8v*>(
            &As[(wr * 64 + m * 16 + l15) * 64 + kk * 32 + lg * 8]));
#pragma unroll
      for (int n = 0; n < 4; ++n)
        b[n] = __builtin_bit_cast(bf16x8, *reinterpret_cast<const short8v*>(
            &Bs[(wc * 64 + n * 16 + l15) * 64 + kk * 32 + lg * 8]));
#pragma unroll
      for (int m = 0; m < 4; ++m)
#pragma unroll
        for (int n = 0; n < 4; ++n)
          acc[m][n] = __builtin_amdgcn_mfma_f32_16x16x32_bf16(a[m], b[n], acc[m][n], 0, 0, 0);
    }
  }

  void* dst;
  int col0, stride;
  if (!SPLIT || bn < Nsplit) {
    dst = C0; col0 = bn; stride = S0;
  } else {
    dst = C1; col0 = bn - Nsplit; stride = S1;
  }
#pragma unroll
  for (int m = 0; m < 4; ++m) {
#pragma unroll
    for (int j = 0; j < 4; ++j) {
      const size_t row = (size_t)(bm + wr * 64 + m * 16 + lg * 4 + j);
#pragma unroll
      for (int n = 0; n < 4; ++n) {
        const int col = col0 + wc * 64 + n * 16 + l15;
        if (BF16_OUT)
          ((unsigned short*)dst)[row * stride + col] = f2bf(acc[m][n][j]);
        else
          ((float*)dst)[row * stride + col] = acc[m][n][j];
      }
    }
  }
}

// ---------------------------------------------------------------------------
__global__ __launch_bounds__(256) void transpose_cast(
    const float* __restrict__ W, unsigned short* __restrict__ Wt, int K, int N) {
  __shared__ float tile[32][33];
  const int tx = threadIdx.x & 31, ty = threadIdx.x >> 5;
  const int n0 = blockIdx.x * 32, k0 = blockIdx.y * 32;
#pragma unroll
  for (int i = 0; i < 4; ++i)
    tile[ty + i * 8][tx] = W[(size_t)(k0 + ty + i * 8) * N + n0 + tx];
  __syncthreads();
#pragma unroll
  for (int i = 0; i < 4; ++i)
    Wt[(size_t)(n0 + ty + i * 8) * K + k0 + tx] = f2bf(tile[tx][ty + i * 8]);
}

__global__ __launch_bounds__(256) void cast_f32_bf16(
    const float* __restrict__ in, unsigned short* __restrict__ out) {
  const int i = (blockIdx.x * 256 + threadIdx.x) * 8;
  float4 a = *reinterpret_cast<const float4*>(&in[i]);
  float4 b = *reinterpret_cast<const float4*>(&in[i + 4]);
  short8v s;
  s[0] = f2bf(a.x); s[1] = f2bf(a.y); s[2] = f2bf(a.z); s[3] = f2bf(a.w);
  s[4] = f2bf(b.x); s[5] = f2bf(b.y); s[6] = f2bf(b.z); s[7] = f2bf(b.w);
  *reinterpret_cast<short8v*>(&out[i]) = s;
}

// ---------------------------------------------------------------------------
__global__ __launch_bounds__(256) void rope_xpos_ip(
    unsigned short* __restrict__ buf, int row_stride, int nh_shift, int invert,
    float extra_scale) {
  const int idx = blockIdx.x * 256 + threadIdx.x;
  const int dp  = idx & 63;
  const int tmp = idx >> 6;
  const int h   = tmp & ((1 << nh_shift) - 1);
  const int row = tmp >> nh_shift;
  const int s   = row & (SLEN - 1);

  const float inv_freq = expf(-(float)dp * (9.210340371976184f / 64.0f));
  const float ang = (float)s * inv_freq;
  float sn, cs;
  sincosf(ang, &sn, &cs);

  unsigned short* p = buf + (size_t)row * row_stride + h * HD;
  const float x0 = bf2f(p[dp]);
  const float x1 = bf2f(p[dp + 64]);
  float y0 = x0 * cs - x1 * sn;
  float y1 = x1 * cs + x0 * sn;

  const float scl = ((float)s + 256.0f) / 512.0f;
  float se_even = invert ? (1.0f / scl) : scl;
  float se_odd  = invert ? scl : (1.0f / scl);
  float se = ((dp & 1) ? se_odd : se_even) * extra_scale;

  p[dp]      = f2bf(y0 * se);
  p[dp + 64] = f2bf(y1 * se);
}

// ---------------------------------------------------------------------------
// Flash attention v7: 512 thr (8 waves), QBLK=128, 32 q-rows/wave via
// mfma_f32_32x32x16_bf16 (swapped operands -> q = lane&31 lane-local softmax,
// in-register P via shfl_xor(32), no P LDS). KV-parity split: waves 0-3 even
// kv tiles, 4-7 odd; 4 tile-buffers (128 KB), K staged by global_load_lds
// with pre-swizzled per-lane source, V reg-staged word-packed d-major.
// One barrier per 2-tile epoch. Final (m,l,O) merge via LDS.
// ---------------------------------------------------------------------------
__global__ __launch_bounds__(512, 1) void flash_attn_v7(
    const unsigned short* __restrict__ qb, const unsigned short* __restrict__ kvb,
    unsigned short* __restrict__ o) {
  const int bid = blockIdx.x;
  const int u   = bid & 15;
  const int qt2 = (u & 1) ? (15 - (u >> 1)) : (u >> 1);  // balanced pairing
  const int bh  = bid >> 4;
  const int h   = bh & (NH - 1);
  const int b   = bh >> 4;
  const int kvh = h >> 2;

  __shared__ __align__(16) unsigned char smem[131072];
  // K bufs: smem + buf*16384 (buf = set*2+par), elem [64][128] swz grp^(row&15)
  // V bufs: smem + 65536 + buf*16384, word [128 d][32 kv-pair] swz ^((d&7)<<2)

  const int t    = threadIdx.x;
  const int lane = t & 63;
  const int w    = t >> 6;    // 0..7
  const int par  = w >> 2;    // kv tile parity
  const int wq   = w & 3;     // q-row group (32 rows)
  const int hi   = lane >> 5;
  const int l31  = lane & 31;

  const size_t bS = (size_t)b * SLEN;

  // ---- Q fragments (B-operand): qf[c] = Q[q = l31-row][c*16 + hi*8 .. +8]
  bf16x8 qf[8];
  {
    const size_t qrow = (bS + qt2 * 128 + wq * 32 + l31) * 2048 + (size_t)h * HD;
#pragma unroll
    for (int c = 0; c < 8; ++c)
      qf[c] = __builtin_bit_cast(bf16x8,
          *reinterpret_cast<const short8v*>(&qb[qrow + c * 16 + hi * 8]));
  }

  // staging ids
  const int vr2 = t & 31;   // V kv row-pair
  const int vg  = t >> 5;   // V d group (0..15)
  int krow[2], kgrp[2];
#pragma unroll
  for (int i = 0; i < 2; ++i) {
    const int slot = w * 2048 + i * 1024 + lane * 16;  // byte slot in K buf
    krow[i] = slot >> 8;
    kgrp[i] = (slot >> 4) & 15;
  }

#define K_STAGE(kt, bufk)                                                      \
  { _Pragma("unroll") for (int i = 0; i < 2; ++i) {                            \
      const unsigned short* ksrc = &kvb[(bS + (size_t)(kt) * 64 + krow[i]) * 1024 \
          + kvh * 128 + ((kgrp[i] ^ (krow[i] & 15)) << 3)];                    \
      __builtin_amdgcn_global_load_lds(                                        \
          (const __attribute__((address_space(1))) unsigned int*)ksrc,         \
          (__attribute__((address_space(3))) unsigned int*)                    \
              (smem + (bufk) * 16384 + w * 2048 + i * 1024),                   \
          16, 0, 0); } }

#define V_LOAD(kt, r0, r1)                                                     \
  { const size_t vb_ = (bS + (size_t)(kt) * 64) * 1024 + kvh * 128 + 512;      \
    r0 = *reinterpret_cast<const short8v*>(                                    \
        &kvb[vb_ + (size_t)(2 * vr2) * 1024 + vg * 8]);                        \
    r1 = *reinterpret_cast<const short8v*>(                                    \
        &kvb[vb_ + (size_t)(2 * vr2 + 1) * 1024 + vg * 8]); }

#define V_WRITE(bufk, r0, r1)                                                  \
  { unsigned int* Vw_ = (unsigned int*)(smem + 65536 + (bufk) * 16384);        \
    _Pragma("unroll") for (int j = 0; j < 8; ++j) {                            \
      const int d = vg * 8 + j;                                                \
      Vw_[d * 32 + (vr2 ^ ((d & 7) << 2))] =                                   \
          (unsigned int)(unsigned short)r0[j] |                                \
          ((unsigned int)(unsigned short)r1[j] << 16); } }

  f32x16 Od[4];
#pragma unroll
  for (int ds = 0; ds < 4; ++ds)
#pragma unroll
    for (int r = 0; r < 16; ++r) Od[ds][r] = 0.f;
  float m_run = -1e30f, l_run = 0.f;

  const int nt = 2 * qt2 + 2;
  short8v va0, va1, vb0, vb1;

  // prologue: stage tiles 0 (buf0) and 1 (buf1)
  K_STAGE(0, 0)
  K_STAGE(1, 1)
  V_LOAD(0, va0, va1)
  V_LOAD(1, vb0, vb1)
  __syncthreads();
  V_WRITE(0, va0, va1)
  V_WRITE(1, vb0, vb1)
  __syncthreads();

  for (int e = 0; e <= qt2; ++e) {
    const int s = e & 1;
    const int kt = 2 * e + par;
    const bool more = (e < qt2);
    if (more) {
      K_STAGE(2 * e + 2, (s ^ 1) * 2 + 0)
      K_STAGE(2 * e + 3, (s ^ 1) * 2 + 1)
      V_LOAD(2 * e + 2, va0, va1)
      V_LOAD(2 * e + 3, vb0, vb1)
    }
    const unsigned short* Kb = (const unsigned short*)(smem + (s * 2 + par) * 16384);
    const unsigned int*   Vw = (const unsigned int*)(smem + 65536 + (s * 2 + par) * 16384);

    // ---- S^T = K @ Q^T : A-frag K[k=l31(+32)][d], B-frag qf.
    f32x16 Sa, Sb;
#pragma unroll
    for (int r = 0; r < 16; ++r) { Sa[r] = 0.f; Sb[r] = 0.f; }
    __builtin_amdgcn_s_setprio(1);
#pragma unroll
    for (int c = 0; c < 8; ++c) {
      const int ra = l31, rb = 32 + l31;
      bf16x8 ka = __builtin_bit_cast(bf16x8, *reinterpret_cast<const short8v*>(
          &Kb[ra * 128 + (((2 * c + hi) ^ (ra & 15)) << 3)]));
      bf16x8 kb2 = __builtin_bit_cast(bf16x8, *reinterpret_cast<const short8v*>(
          &Kb[rb * 128 + (((2 * c + hi) ^ (rb & 15)) << 3)]));
      Sa = __builtin_amdgcn_mfma_f32_32x32x16_bf16(ka, qf[c], Sa, 0, 0, 0);
      Sb = __builtin_amdgcn_mfma_f32_32x32x16_bf16(kb2, qf[c], Sb, 0, 0, 0);
    }
    __builtin_amdgcn_s_setprio(0);

    // ---- causal mask (only last two tiles can mask)
    if (kt >= 2 * qt2) {
      const int thresh = qt2 * 128 + wq * 32 + l31 - kt * 64;
#pragma unroll
      for (int r = 0; r < 16; ++r) {
        const int kla = (r & 3) + 8 * (r >> 2) + 4 * hi;
        if (kla > thresh) Sa[r] = -INFINITY;
        if (kla + 32 > thresh) Sb[r] = -INFINITY;
      }
    }

    // ---- lane-local softmax (q = l31; partner half via shfl_xor 32)
    float pmax = Sa[0];
#pragma unroll
    for (int r = 0; r < 16; ++r) pmax = fmaxf(pmax, fmaxf(Sa[r], Sb[r]));
    pmax = fmaxf(pmax, __shfl_xor(pmax, 32));

    const bool defer = __all(pmax - m_run <= 8.0f);
    float m_new, f;
    if (defer) {
      m_new = m_run; f = 1.0f;
    } else {
      m_new = fmaxf(m_run, pmax);
      f = __expf(m_run - m_new);
      m_run = m_new;
    }

    float psum = 0.f;
#pragma unroll
    for (int r = 0; r < 16; ++r) {
      Sa[r] = __expf(Sa[r] - m_new);
      Sb[r] = __expf(Sb[r] - m_new);
      psum += Sa[r] + Sb[r];
    }
    psum += __shfl_xor(psum, 32);
    l_run = l_run * f + psum;

    if (!defer) {
#pragma unroll
      for (int ds = 0; ds < 4; ++ds)
#pragma unroll
        for (int r = 0; r < 16; ++r) Od[ds][r] *= f;
    }

    // ---- O^T += V^T @ P^T  (P packed in-register, half-swap via shfl_xor 32)
#pragma unroll
    for (int kc = 0; kc < 4; ++kc) {
      const int Zz = kc & 1;
      f32x16 Sx = (kc >> 1) ? Sb : Sa;
      unsigned int W00 = pk2(Sx[4 * (2 * Zz + 0) + 0], Sx[4 * (2 * Zz + 0) + 1]);
      unsigned int W01 = pk2(Sx[4 * (2 * Zz + 0) + 2], Sx[4 * (2 * Zz + 0) + 3]);
      unsigned int W10 = pk2(Sx[4 * (2 * Zz + 1) + 0], Sx[4 * (2 * Zz + 1) + 1]);
      unsigned int W11 = pk2(Sx[4 * (2 * Zz + 1) + 2], Sx[4 * (2 * Zz + 1) + 3]);
      unsigned int X00 = __shfl_xor(W00, 32), X01 = __shfl_xor(W01, 32);
      unsigned int X10 = __shfl_xor(W10, 32), X11 = __shfl_xor(W11, 32);
      u32x4 pv;
      pv[0] = hi ? X10 : W00;
      pv[1] = hi ? X11 : W01;
      pv[2] = hi ? W10 : X00;
      pv[3] = hi ? W11 : X01;
      bf16x8 pf = __builtin_bit_cast(bf16x8, pv);
      __builtin_amdgcn_s_setprio(1);
#pragma unroll
      for (int ds = 0; ds < 4; ++ds) {
        const int d = ds * 32 + l31;
        u32x4 vv = *reinterpret_cast<const u32x4*>(
            &Vw[d * 32 + ((kc * 8 + hi * 4) ^ ((d & 7) << 2))]);
        bf16x8 vf = __builtin_bit_cast(bf16x8, vv);
        Od[ds] = __builtin_amdgcn_mfma_f32_32x32x16_bf16(vf, pf, Od[ds], 0, 0, 0);
      }
      __builtin_amdgcn_s_setprio(0);
    }

    if (more) {
      V_WRITE((s ^ 1) * 2 + 0, va0, va1)
      V_WRITE((s ^ 1) * 2 + 1, vb0, vb1)
    }
    __syncthreads();
  }

  // ---- merge parity halves (pairs: wave wq <- wave wq+4), then store
  __syncthreads();
  float* mf = (float*)smem;               // [wq][2][64]
  float* Of = (float*)(smem + 2048);      // [wq][ds][reg][64]
  if (par == 1) {
    mf[(wq * 2 + 0) * 64 + lane] = m_run;
    mf[(wq * 2 + 1) * 64 + lane] = l_run;
#pragma unroll
    for (int ds = 0; ds < 4; ++ds)
#pragma unroll
      for (int r = 0; r < 16; ++r)
        Of[((wq * 4 + ds) * 16 + r) * 64 + lane] = Od[ds][r];
  }
  __syncthreads();
  if (par == 0) {
    const float m_o = mf[(wq * 2 + 0) * 64 + lane];
    const float l_o = mf[(wq * 2 + 1) * 64 + lane];
    const float mm = fmaxf(m_run, m_o);
    const float fe = __expf(m_run - mm);
    const float fo = __expf(m_o - mm);
    const float linv = 1.0f / (l_run * fe + l_o * fo);
    const size_t row = bS + qt2 * 128 + wq * 32 + l31;
#pragma unroll
    for (int ds = 0; ds < 4; ++ds) {
#pragma unroll
      for (int g = 0; g < 4; ++g) {
        short4v ov;
#pragma unroll
        for (int j = 0; j < 4; ++j) {
          const int r = g * 4 + j;
          const float val = (Od[ds][r] * fe +
                             Of[((wq * 4 + ds) * 16 + r) * 64 + lane] * fo) * linv;
          ov[j] = (short)__builtin_bit_cast(unsigned short, (__bf16)val);
        }
        const int dbase = ds * 32 + 8 * g + 4 * hi;
        *reinterpret_cast<short4v*>(&o[row * 2048 + h * HD + dbase]) = ov;
      }
    }
  }
#undef K_STAGE
#undef V_LOAD
#undef V_WRITE
}

// ---------------------------------------------------------------------------
extern "C" void kernel_launch(void* const* d_in, const int* in_sizes, int n_in,
                              void* d_out, int out_size, void* d_ws, size_t ws_size,
                              hipStream_t stream) {
  (void)in_sizes; (void)n_in; (void)out_size; (void)ws_size;
  const float* x  = (const float*)d_in[0];
  const float* Wq = (const float*)d_in[1];
  const float* Wk = (const float*)d_in[2];
  const float* Wv = (const float*)d_in[3];
  const float* Wo = (const float*)d_in[4];
  float* out = (float*)d_out;

  unsigned char* ws = (unsigned char*)d_ws;
  const size_t MB = 1024 * 1024;
  unsigned short* xb    = (unsigned short*)(ws);            // 16 MB 4096x2048
  unsigned short* Wqkvt = (unsigned short*)(ws + 16 * MB);  // 12 MB 3072x2048
  unsigned short* Wot   = (unsigned short*)(ws + 28 * MB);  //  8 MB 2048x2048
  unsigned short* qb    = (unsigned short*)(ws + 36 * MB);  // 16 MB 4096x2048
  unsigned short* kvb   = (unsigned short*)(ws + 52 * MB);  //  8 MB 4096x1024
  unsigned short* attn  = (unsigned short*)(ws + 60 * MB);  // 16 MB

  const int M = BDIM * SLEN;  // 4096
  dim3 blk(256);

  cast_f32_bf16<<<(M * 2048) / (256 * 8), blk, 0, stream>>>(x, xb);
  transpose_cast<<<dim3(64, 64), blk, 0, stream>>>(Wq, Wqkvt, 2048, 2048);
  transpose_cast<<<dim3(16, 64), blk, 0, stream>>>(
      Wk, Wqkvt + (size_t)2048 * 2048, 2048, 512);
  transpose_cast<<<dim3(16, 64), blk, 0, stream>>>(
      Wv, Wqkvt + (size_t)2560 * 2048, 2048, 512);
  transpose_cast<<<dim3(64, 64), blk, 0, stream>>>(Wo, Wot, 2048, 2048);

  gemm_mfma_bt<true, true><<<dim3(24, 32), blk, 0, stream>>>(
      xb, Wqkvt, qb, kvb, M, 3072, 2048, 2048, 2048, 1024);

  rope_xpos_ip<<<(M * NH * 64) / 256, blk, 0, stream>>>(
      qb, 2048, 4, 0, 0.088388347648318447f);
  rope_xpos_ip<<<(M * NKV * 64) / 256, blk, 0, stream>>>(kvb, 1024, 2, 1, 1.0f);

  flash_attn_v7<<<BDIM * NH * (SLEN / 128), dim3(512), 0, stream>>>(qb, kvb, attn);

  gemm_mfma_bt<false, false><<<dim3(16, 32), blk, 0, stream>>>(
      attn, Wot, out, nullptr, M, 2048, 2048, 2048, 2048, 0);
}